// Round 1
// baseline (443.042 us; speedup 1.0000x reference)
//
#include <hip/hip_runtime.h>
#include <cfloat>
#include <math.h>

// Problem constants (z: [16,64,64,256] fp32, codebook: [1024,256] fp32)
#define P_TOT 65536
#define DIM   256
#define KTOT  1024
#define BETA_ 0.25f
#define EPS_  1e-5f
// flag threshold: >= 2*(2*delta_ze) + 2*ULP(dist) with worst-case
// delta_ze <= ~8e-6 (3-term bf16 split + ref fp32 err) and ULP <= 3.05e-5.
#define MARGIN_ 1.5e-4f

// d_out layout (float32, concatenated in reference return order):
// [0, P*D) z_q_st | [P*D+0..3] losses+perplexity | [P*D+4, +P) indices
#define OUT_LOSS_OFF ((size_t)P_TOT * DIM)
#define OUT_IDX_OFF  (OUT_LOSS_OFF + 4)

typedef __attribute__((ext_vector_type(8))) short s16x8;   // 8 bf16 (4 VGPRs)
typedef __attribute__((ext_vector_type(4))) float f32x4;   // MFMA acc

__device__ __forceinline__ unsigned short f2bf(float x) {  // RNE f32->bf16
    unsigned u = __float_as_uint(x);
    u += 0x7FFFu + ((u >> 16) & 1u);
    return (unsigned short)(u >> 16);
}
__device__ __forceinline__ float bf2f(unsigned short h) {
    return __uint_as_float(((unsigned)h) << 16);
}

// ---------------- prep: e2[k], codebook hi/lo split, zero hist/loss/flags ---
__global__ __launch_bounds__(64) void vq_prep(const float* __restrict__ cb,
                                              float* __restrict__ e2,
                                              unsigned short* __restrict__ cbh,
                                              unsigned short* __restrict__ cbl,
                                              unsigned int* __restrict__ hist,
                                              float* __restrict__ loss_sum,
                                              unsigned int* __restrict__ flag_cnt) {
    const int k = blockIdx.x;
    const int lane = threadIdx.x;
    float4 v = *(const float4*)(cb + (size_t)k * DIM + lane * 4);
    float s = v.x * v.x + v.y * v.y + v.z * v.z + v.w * v.w;
    #pragma unroll
    for (int off = 32; off > 0; off >>= 1) s += __shfl_down(s, off, 64);
    if (lane == 0) e2[k] = s;

    unsigned short h0 = f2bf(v.x), h1 = f2bf(v.y), h2 = f2bf(v.z), h3 = f2bf(v.w);
    unsigned short l0 = f2bf(v.x - bf2f(h0)), l1 = f2bf(v.y - bf2f(h1));
    unsigned short l2 = f2bf(v.z - bf2f(h2)), l3 = f2bf(v.w - bf2f(h3));
    uint2 hp, lp;
    hp.x = (unsigned)h0 | ((unsigned)h1 << 16); hp.y = (unsigned)h2 | ((unsigned)h3 << 16);
    lp.x = (unsigned)l0 | ((unsigned)l1 << 16); lp.y = (unsigned)l2 | ((unsigned)l3 << 16);
    *(uint2*)(cbh + (size_t)k * DIM + lane * 4) = hp;
    *(uint2*)(cbl + (size_t)k * DIM + lane * 4) = lp;

    const int gid = k * 64 + lane;
    if (gid < KTOT) hist[gid] = 0u;
    if (gid == KTOT) { *loss_sum = 0.0f; *flag_cnt = 0u; }
}

// ---------------- z2[p] = sum(z[p]^2), one wave per pixel -------------------
__global__ __launch_bounds__(256) void vq_z2(const float* __restrict__ z,
                                             float* __restrict__ z2) {
    const int lane = threadIdx.x & 63;
    const int wave = threadIdx.x >> 6;
    const int p = blockIdx.x * 4 + wave;
    float4 v = *(const float4*)(z + (size_t)p * DIM + lane * 4);
    float s = v.x * v.x + v.y * v.y + v.z * v.z + v.w * v.w;
    #pragma unroll
    for (int off = 32; off > 0; off >>= 1) s += __shfl_down(s, off, 64);
    if (lane == 0) z2[p] = s;
}

// ---------------- main: bf16x2 split MFMA GEMM-argmin + margin flag ---------
// block: 256 thr (4 waves, 2x2 wave grid, 64x64 wave tile of 16x16 frags)
// tile: BM=128 pixels x BN=128 codes per n-chunk, full N looped in-block.
#define BM 128
#define BN 128

__global__ __launch_bounds__(256, 2) void vq_argmin(
    const float* __restrict__ z, const float* __restrict__ cb,
    const unsigned short* __restrict__ cbh, const unsigned short* __restrict__ cbl,
    const float* __restrict__ z2, const float* __restrict__ e2,
    unsigned int* __restrict__ hist, float* __restrict__ loss_sum,
    unsigned int* __restrict__ flag_cnt, unsigned int* __restrict__ flag_list,
    float* __restrict__ out)
{
    // LDS: 4 bf16 tiles [128][64] (Ah,Al,Bh,Bl) = 64KB, reused as reduction
    __shared__ __align__(16) char sm[65536];
    __shared__ int kwin[BM];
    __shared__ unsigned char flgs[BM];
    __shared__ float wred[4];

    const int tid = threadIdx.x;
    const int lane = tid & 63;
    const int wid = tid >> 6;
    const int wm = wid >> 1, wn = wid & 1;
    const int col = lane & 15;      // frag column (n for B/D, m-row for A reads)
    const int lg  = lane >> 4;      // k-group / D-row group
    const int swz = lane & 7;
    const int row0 = blockIdx.x * BM;

    // persistent per-thread state: 16 pixels x (best, 2nd-best, idx)
    float b1[16], b2[16]; int i1[16];
    float z2r[16];
    #pragma unroll
    for (int q = 0; q < 16; ++q) {
        b1[q] = FLT_MAX; b2[q] = FLT_MAX; i1[q] = 0;
        z2r[q] = z2[row0 + wm * 64 + (q >> 2) * 16 + lg * 4 + (q & 3)];
    }

    int aRow[4], bRow[4];
    #pragma unroll
    for (int f = 0; f < 4; ++f) {
        aRow[f] = (wm * 64 + f * 16 + col) * 128;   // byte base of LDS row
        bRow[f] = (wn * 64 + f * 16 + col) * 128;
    }
    const int bc0 = ((0 + lg) ^ swz) << 4;          // 16B-block col, ks=0
    const int bc1 = ((4 + lg) ^ swz) << 4;          // ks=1

    #pragma unroll 1
    for (int nc = 0; nc < KTOT / BN; ++nc) {
        const int n0 = nc * BN;
        f32x4 acc[4][4];
        #pragma unroll
        for (int fm = 0; fm < 4; ++fm)
            #pragma unroll
            for (int fn = 0; fn < 4; ++fn)
                acc[fm][fn] = (f32x4){0.0f, 0.0f, 0.0f, 0.0f};

        #pragma unroll 1
        for (int kc = 0; kc < 4; ++kc) {            // BK=64
            __syncthreads();
            // --- stage A: fp32 z -> bf16 hi/lo, swizzled LDS write ---------
            #pragma unroll
            for (int i = 0; i < 8; ++i) {
                const int id = i * 256 + tid;
                const int r = id >> 4, c4 = id & 15;
                float4 v = *(const float4*)(z + (size_t)(row0 + r) * DIM + kc * 64 + c4 * 4);
                unsigned short h0 = f2bf(v.x), h1 = f2bf(v.y), h2 = f2bf(v.z), h3 = f2bf(v.w);
                unsigned short m0 = f2bf(v.x - bf2f(h0)), m1 = f2bf(v.y - bf2f(h1));
                unsigned short m2 = f2bf(v.z - bf2f(h2)), m3 = f2bf(v.w - bf2f(h3));
                uint2 hp, lp;
                hp.x = (unsigned)h0 | ((unsigned)h1 << 16);
                hp.y = (unsigned)h2 | ((unsigned)h3 << 16);
                lp.x = (unsigned)m0 | ((unsigned)m1 << 16);
                lp.y = (unsigned)m2 | ((unsigned)m3 << 16);
                const int byt = r * 128 + (((c4 >> 1) ^ (r & 7)) << 4) + ((c4 & 1) << 3);
                *(uint2*)(sm + byt) = hp;               // Ah @ 0
                *(uint2*)(sm + 16384 + byt) = lp;       // Al @ 16K
            }
            // --- stage B: pre-split codebook hi/lo, swizzled LDS write -----
            #pragma unroll
            for (int i = 0; i < 4; ++i) {
                const int id = i * 256 + tid;
                const int r = id >> 3, kb = id & 7;
                const size_t gb = (size_t)(n0 + r) * 512 + kc * 128 + kb * 16;
                uint4 vh = *(const uint4*)((const char*)cbh + gb);
                uint4 vl = *(const uint4*)((const char*)cbl + gb);
                const int byt = r * 128 + ((kb ^ (r & 7)) << 4);
                *(uint4*)(sm + 32768 + byt) = vh;       // Bh @ 32K
                *(uint4*)(sm + 49152 + byt) = vl;       // Bl @ 48K
            }
            __syncthreads();
            // --- MFMA: 3-term bf16x2 split into shared f32 accumulator ----
            #pragma unroll
            for (int ks = 0; ks < 2; ++ks) {
                const int bc = ks ? bc1 : bc0;
                s16x8 ah[4], al[4], bh[4], bl[4];
                #pragma unroll
                for (int f = 0; f < 4; ++f) {
                    ah[f] = *(const s16x8*)(sm + aRow[f] + bc);
                    al[f] = *(const s16x8*)(sm + 16384 + aRow[f] + bc);
                    bh[f] = *(const s16x8*)(sm + 32768 + bRow[f] + bc);
                    bl[f] = *(const s16x8*)(sm + 49152 + bRow[f] + bc);
                }
                #pragma unroll
                for (int fm = 0; fm < 4; ++fm)
                    #pragma unroll
                    for (int fn = 0; fn < 4; ++fn) {
                        acc[fm][fn] = __builtin_amdgcn_mfma_f32_16x16x32_bf16(
                            ah[fm], bh[fn], acc[fm][fn], 0, 0, 0);
                        acc[fm][fn] = __builtin_amdgcn_mfma_f32_16x16x32_bf16(
                            ah[fm], bl[fn], acc[fm][fn], 0, 0, 0);
                        acc[fm][fn] = __builtin_amdgcn_mfma_f32_16x16x32_bf16(
                            al[fm], bh[fn], acc[fm][fn], 0, 0, 0);
                    }
            }
        }
        // --- fold chunk into running (best, 2nd); ref dist rounding --------
        float e2v[4];
        #pragma unroll
        for (int fn = 0; fn < 4; ++fn) e2v[fn] = e2[n0 + wn * 64 + fn * 16 + col];
        #pragma unroll
        for (int fm = 0; fm < 4; ++fm)
            #pragma unroll
            for (int fn = 0; fn < 4; ++fn)
                #pragma unroll
                for (int r4 = 0; r4 < 4; ++r4) {
                    const int q = fm * 4 + r4;
                    const float dist = (z2r[q] + e2v[fn]) - 2.0f * acc[fm][fn][r4];
                    const int idx = n0 + wn * 64 + fn * 16 + col;
                    if (dist < b1[q]) { b2[q] = b1[q]; b1[q] = dist; i1[q] = idx; }
                    else if (dist < b2[q]) { b2[q] = dist; }
                }
    }

    // --- cross-thread reduction of (b1,i1,b2); slots padded to 33 ----------
    __syncthreads();
    float* Rb1 = (float*)sm;                 // [128][33]
    float* Rb2 = (float*)(sm + 16896);
    int*   Ri1 = (int*)(sm + 33792);
    const int slot = col + 16 * wn;          // 0..31
    #pragma unroll
    for (int q = 0; q < 16; ++q) {
        const int px = wm * 64 + (q >> 2) * 16 + lg * 4 + (q & 3);
        Rb1[px * 33 + slot] = b1[q];
        Rb2[px * 33 + slot] = b2[q];
        Ri1[px * 33 + slot] = i1[q];
    }
    __syncthreads();
    if (tid < BM) {
        float x1 = Rb1[tid * 33], x2 = Rb2[tid * 33]; int xi = Ri1[tid * 33];
        for (int s = 1; s < 32; ++s) {
            const float c1 = Rb1[tid * 33 + s], c2 = Rb2[tid * 33 + s];
            const int ci = Ri1[tid * 33 + s];
            const float nb2 = fminf(fmaxf(x1, c1), fminf(x2, c2));
            if (c1 < x1 || (c1 == x1 && ci < xi)) { x1 = c1; xi = ci; }
            x2 = nb2;
        }
        kwin[tid] = xi;
        const bool fl = (x2 - x1) <= MARGIN_;
        flgs[tid] = fl ? 1 : 0;
        if (fl) {
            const unsigned pos = atomicAdd(flag_cnt, 1u);
            flag_list[pos] = (unsigned)(row0 + tid);
        } else {
            out[OUT_IDX_OFF + row0 + tid] = (float)xi;
            atomicAdd(&hist[xi], 1u);
        }
    }
    __syncthreads();

    // --- epilogue for UNFLAGGED rows (exact fp32, ref rounding) ------------
    float lacc = 0.0f;
    #pragma unroll 4
    for (int i = 0; i < 32; ++i) {
        const int flat4 = tid + i * 256;
        const int row = flat4 >> 6;            // wave-uniform
        if (!flgs[row]) {
            const int dj = (flat4 & 63) * 4;
            const size_t zoff = (size_t)(row0 + row) * DIM + dj;
            float4 zv = *(const float4*)(z + zoff);
            float4 ev = *(const float4*)(cb + (size_t)kwin[row] * DIM + dj);
            float dx = ev.x - zv.x, dy = ev.y - zv.y, dz = ev.z - zv.z, dw = ev.w - zv.w;
            float4 o;
            o.x = zv.x + dx; o.y = zv.y + dy; o.z = zv.z + dz; o.w = zv.w + dw;
            *(float4*)(out + zoff) = o;
            lacc += dx * dx + dy * dy + dz * dz + dw * dw;
        }
    }
    #pragma unroll
    for (int off = 32; off > 0; off >>= 1) lacc += __shfl_down(lacc, off, 64);
    if (lane == 0) wred[wid] = lacc;
    __syncthreads();
    if (tid == 0) atomicAdd(loss_sum, wred[0] + wred[1] + wred[2] + wred[3]);
}

// ---------------- repair: exact fp32 re-argmin + epilogue for flagged ------
// Bit-identical to the verified baseline's fp32 path: d-ascending fma chain,
// dist = (z2+e2[k]) - 2*dot, tie -> smaller index. 4 pixels per block so the
// codebook is read once per 4 pixels.
__global__ __launch_bounds__(256) void vq_fix(
    const float* __restrict__ z, const float* __restrict__ cb,
    const float* __restrict__ z2, const float* __restrict__ e2,
    const unsigned int* __restrict__ flag_cnt, const unsigned int* __restrict__ flag_list,
    unsigned int* __restrict__ hist, float* __restrict__ loss_sum,
    float* __restrict__ out)
{
    __shared__ float zrow[4][DIM];
    __shared__ float zz2[4];
    __shared__ int pxid[4];
    __shared__ float rb[4][256];
    __shared__ int   ri[4][256];
    __shared__ int   kw4[4];

    const int tid = threadIdx.x;
    const int total = (int)*flag_cnt;

    for (int base = blockIdx.x * 4; base < total; base += gridDim.x * 4) {
        const int npx = min(4, total - base);
        __syncthreads();                       // protect prev iter's shared
        if (tid < 4) {
            const int p = (int)flag_list[base + (tid < npx ? tid : 0)];
            pxid[tid] = p; zz2[tid] = z2[p];
        }
        __syncthreads();
        {
            const int q = tid >> 6, d = (tid & 63) * 4;
            float4 v = *(const float4*)(z + (size_t)pxid[q] * DIM + d);
            *(float4*)&zrow[q][d] = v;
        }
        __syncthreads();

        const int k0 = tid * 4;
        float acc[4][4];
        #pragma unroll
        for (int q = 0; q < 4; ++q)
            #pragma unroll
            for (int j = 0; j < 4; ++j) acc[q][j] = 0.0f;

        for (int d4 = 0; d4 < 64; ++d4) {
            float4 cv[4];
            #pragma unroll
            for (int j = 0; j < 4; ++j)
                cv[j] = *(const float4*)(cb + (size_t)(k0 + j) * DIM + d4 * 4);
            #pragma unroll
            for (int q = 0; q < 4; ++q) {
                float4 zv = *(const float4*)&zrow[q][d4 * 4];
                #pragma unroll
                for (int j = 0; j < 4; ++j) {
                    acc[q][j] = fmaf(zv.x, cv[j].x, acc[q][j]);
                    acc[q][j] = fmaf(zv.y, cv[j].y, acc[q][j]);
                    acc[q][j] = fmaf(zv.z, cv[j].z, acc[q][j]);
                    acc[q][j] = fmaf(zv.w, cv[j].w, acc[q][j]);
                }
            }
        }
        #pragma unroll
        for (int q = 0; q < 4; ++q) {
            float bd = FLT_MAX; int bi = 0;
            #pragma unroll
            for (int j = 0; j < 4; ++j) {       // k ascending -> strict <
                const int k = k0 + j;
                const float dist = (zz2[q] + e2[k]) - 2.0f * acc[q][j];
                if (dist < bd) { bd = dist; bi = k; }
            }
            rb[q][tid] = bd; ri[q][tid] = bi;
        }
        __syncthreads();
        {
            const int q = tid >> 6, lane = tid & 63;
            float bd = rb[q][lane]; int bi = ri[q][lane];
            #pragma unroll
            for (int s = 1; s < 4; ++s) {
                const float d2 = rb[q][lane + s * 64]; const int i2 = ri[q][lane + s * 64];
                if (d2 < bd || (d2 == bd && i2 < bi)) { bd = d2; bi = i2; }
            }
            #pragma unroll
            for (int off = 32; off > 0; off >>= 1) {
                const float d2 = __shfl_down(bd, off, 64);
                const int i2 = __shfl_down(bi, off, 64);
                if (d2 < bd || (d2 == bd && i2 < bi)) { bd = d2; bi = i2; }
            }
            if (lane == 0) kw4[q] = bi;
        }
        __syncthreads();
        {
            const int q = tid >> 6, lane = tid & 63;
            if (q < npx) {
                const int p = pxid[q];
                const int kw = kw4[q];
                const int d = lane * 4;
                float4 zv = *(const float4*)&zrow[q][d];
                float4 ev = *(const float4*)(cb + (size_t)kw * DIM + d);
                float dx = ev.x - zv.x, dy = ev.y - zv.y, dz = ev.z - zv.z, dw = ev.w - zv.w;
                float4 o;
                o.x = zv.x + dx; o.y = zv.y + dy; o.z = zv.z + dz; o.w = zv.w + dw;
                *(float4*)(out + (size_t)p * DIM + d) = o;
                float lacc = dx * dx + dy * dy + dz * dz + dw * dw;
                #pragma unroll
                for (int off = 32; off > 0; off >>= 1) lacc += __shfl_down(lacc, off, 64);
                if (lane == 0) {
                    atomicAdd(loss_sum, lacc);
                    out[OUT_IDX_OFF + p] = (float)kw;
                    atomicAdd(&hist[kw], 1u);
                }
            }
        }
    }
}

// ---------------- finalize: losses + perplexity -----------------------------
__global__ __launch_bounds__(1024) void vq_finalize(
    const unsigned int* __restrict__ hist, const float* __restrict__ loss_sum,
    float* __restrict__ out)
{
    __shared__ float sred[16];
    __shared__ float totalsh;
    const int tid = threadIdx.x;
    const float c = (float)hist[tid];

    float t = c;
    #pragma unroll
    for (int off = 32; off > 0; off >>= 1) t += __shfl_down(t, off, 64);
    if ((tid & 63) == 0) sred[tid >> 6] = t;
    __syncthreads();
    if (tid == 0) {
        float s = 0.0f;
        for (int i = 0; i < 16; ++i) s += sred[i];
        totalsh = s;
    }
    __syncthreads();
    const float total = totalsh;
    const float prob = c / (total + EPS_);
    float term = prob * logf(prob + EPS_);
    __syncthreads();
    #pragma unroll
    for (int off = 32; off > 0; off >>= 1) term += __shfl_down(term, off, 64);
    if ((tid & 63) == 0) sred[tid >> 6] = term;
    __syncthreads();
    if (tid == 0) {
        float s = 0.0f;
        for (int i = 0; i < 16; ++i) s += sred[i];
        const float perp = expf(-s);
        const float S = *loss_sum;
        const float mean = S / (float)(P_TOT * DIM);
        out[OUT_LOSS_OFF + 0] = mean;                  // commitment_loss
        out[OUT_LOSS_OFF + 1] = mean;                  // codebook_loss
        out[OUT_LOSS_OFF + 2] = mean + BETA_ * mean;   // cluster_loss
        out[OUT_LOSS_OFF + 3] = perp;                  // perplexity
    }
}

extern "C" void kernel_launch(void* const* d_in, const int* in_sizes, int n_in,
                              void* d_out, int out_size, void* d_ws, size_t ws_size,
                              hipStream_t stream) {
    const float* z  = (const float*)d_in[0];
    const float* cb = (const float*)d_in[1];
    float* out = (float*)d_out;

    // ws: z2[P] | e2[K] | hist[K] | loss_sum | flag_cnt | flag_list[P] |
    //     cbh[K*D] bf16 | cbl[K*D] bf16   (~1.6 MiB)
    float* z2 = (float*)d_ws;
    float* e2 = z2 + P_TOT;
    unsigned int* hist = (unsigned int*)(e2 + KTOT);
    float* loss_sum = (float*)(hist + KTOT);
    unsigned int* flag_cnt = (unsigned int*)(loss_sum + 1);
    unsigned int* flag_list = flag_cnt + 1;
    unsigned short* cbh = (unsigned short*)(((uintptr_t)(flag_list + P_TOT) + 15) & ~(uintptr_t)15);
    unsigned short* cbl = cbh + (size_t)KTOT * DIM;

    vq_prep<<<KTOT, 64, 0, stream>>>(cb, e2, cbh, cbl, hist, loss_sum, flag_cnt);
    vq_z2<<<P_TOT / 4, 256, 0, stream>>>(z, z2);
    vq_argmin<<<P_TOT / BM, 256, 0, stream>>>(z, cb, cbh, cbl, z2, e2,
                                              hist, loss_sum, flag_cnt, flag_list, out);
    vq_fix<<<512, 256, 0, stream>>>(z, cb, z2, e2, flag_cnt, flag_list,
                                    hist, loss_sum, out);
    vq_finalize<<<1, 1024, 0, stream>>>(hist, loss_sum, out);
}

// Round 2
// 381.801 us; speedup vs baseline: 1.1604x; 1.1604x over previous
//
#include <hip/hip_runtime.h>
#include <cfloat>
#include <math.h>

// Problem constants (z: [16,64,64,256] fp32, codebook: [1024,256] fp32)
#define P_TOT 65536
#define DIM   256
#define KTOT  1024
#define BETA_ 0.25f
#define EPS_  1e-5f
// flag threshold: >= 2*(2*delta_ze) + 2*ULP(dist) with worst-case
// delta_ze <= ~8e-6 (3-term bf16 split + ref fp32 err) and ULP <= 3.05e-5.
#define MARGIN_ 1.5e-4f

// d_out layout (float32, concatenated in reference return order):
// [0, P*D) z_q_st | [P*D+0..3] losses+perplexity | [P*D+4, +P) indices
// NOTE: vq_zsplit temporarily stores zh/zl bf16 (512B+512B per row) in the
// z_q_st region; each argmin block consumes only its own 128 rows before
// overwriting them with the real z_q_st (flagged rows are finished by vq_fix).
#define OUT_LOSS_OFF ((size_t)P_TOT * DIM)
#define OUT_IDX_OFF  (OUT_LOSS_OFF + 4)

typedef __attribute__((ext_vector_type(8))) short s16x8;   // 8 bf16 (4 VGPRs)
typedef __attribute__((ext_vector_type(4))) float f32x4;   // MFMA acc

__device__ __forceinline__ unsigned short f2bf(float x) {  // RNE f32->bf16
    unsigned u = __float_as_uint(x);
    u += 0x7FFFu + ((u >> 16) & 1u);
    return (unsigned short)(u >> 16);
}
__device__ __forceinline__ float bf2f(unsigned short h) {
    return __uint_as_float(((unsigned)h) << 16);
}
// async global->LDS direct copy, 16B per lane; lds ptr MUST be wave-uniform.
__device__ __forceinline__ void gl16(const void* g, void* l) {
    __builtin_amdgcn_global_load_lds(
        (const __attribute__((address_space(1))) unsigned int*)g,
        (__attribute__((address_space(3))) unsigned int*)l, 16, 0, 0);
}

// ---------------- prep: e2[k], codebook hi/lo split, zero hist/loss/flags ---
__global__ __launch_bounds__(64) void vq_prep(const float* __restrict__ cb,
                                              float* __restrict__ e2,
                                              unsigned short* __restrict__ cbh,
                                              unsigned short* __restrict__ cbl,
                                              unsigned int* __restrict__ hist,
                                              float* __restrict__ loss_sum,
                                              unsigned int* __restrict__ flag_cnt) {
    const int k = blockIdx.x;
    const int lane = threadIdx.x;
    float4 v = *(const float4*)(cb + (size_t)k * DIM + lane * 4);
    float s = v.x * v.x + v.y * v.y + v.z * v.z + v.w * v.w;
    #pragma unroll
    for (int off = 32; off > 0; off >>= 1) s += __shfl_down(s, off, 64);
    if (lane == 0) e2[k] = s;

    unsigned short h0 = f2bf(v.x), h1 = f2bf(v.y), h2 = f2bf(v.z), h3 = f2bf(v.w);
    unsigned short l0 = f2bf(v.x - bf2f(h0)), l1 = f2bf(v.y - bf2f(h1));
    unsigned short l2 = f2bf(v.z - bf2f(h2)), l3 = f2bf(v.w - bf2f(h3));
    uint2 hp, lp;
    hp.x = (unsigned)h0 | ((unsigned)h1 << 16); hp.y = (unsigned)h2 | ((unsigned)h3 << 16);
    lp.x = (unsigned)l0 | ((unsigned)l1 << 16); lp.y = (unsigned)l2 | ((unsigned)l3 << 16);
    *(uint2*)(cbh + (size_t)k * DIM + lane * 4) = hp;
    *(uint2*)(cbl + (size_t)k * DIM + lane * 4) = lp;

    const int gid = k * 64 + lane;
    if (gid < KTOT) hist[gid] = 0u;
    if (gid == KTOT) { *loss_sum = 0.0f; *flag_cnt = 0u; }
}

// ------- z2[p] = sum(z[p]^2) AND z hi/lo bf16 split into out-scratch --------
// out row p: bytes [p*1024, p*1024+512) = zh, [p*1024+512, p*1024+1024) = zl
__global__ __launch_bounds__(256) void vq_zsplit(const float* __restrict__ z,
                                                 float* __restrict__ z2,
                                                 float* __restrict__ out) {
    const int lane = threadIdx.x & 63;
    const int wave = threadIdx.x >> 6;
    const int p = blockIdx.x * 4 + wave;
    float4 v = *(const float4*)(z + (size_t)p * DIM + lane * 4);
    float s = v.x * v.x + v.y * v.y + v.z * v.z + v.w * v.w;
    #pragma unroll
    for (int off = 32; off > 0; off >>= 1) s += __shfl_down(s, off, 64);
    if (lane == 0) z2[p] = s;

    unsigned short h0 = f2bf(v.x), h1 = f2bf(v.y), h2 = f2bf(v.z), h3 = f2bf(v.w);
    unsigned short l0 = f2bf(v.x - bf2f(h0)), l1 = f2bf(v.y - bf2f(h1));
    unsigned short l2 = f2bf(v.z - bf2f(h2)), l3 = f2bf(v.w - bf2f(h3));
    uint2 hp, lp;
    hp.x = (unsigned)h0 | ((unsigned)h1 << 16); hp.y = (unsigned)h2 | ((unsigned)h3 << 16);
    lp.x = (unsigned)l0 | ((unsigned)l1 << 16); lp.y = (unsigned)l2 | ((unsigned)l3 << 16);
    char* rowb = (char*)out + (size_t)p * 1024;
    *(uint2*)(rowb + lane * 8) = hp;
    *(uint2*)(rowb + 512 + lane * 8) = lp;
}

// ---------------- main: bf16x2 split MFMA GEMM-argmin + margin flag ---------
// block: 256 thr (4 waves, 2x2 wave grid, 64x64 wave tile of 16x16 frags)
// tile: BM=128 pixels x BN=128 codes per n-chunk, full N looped in-block.
// Staging is pure global_load_lds (no VALU): XOR-16B swizzle applied on the
// per-lane GLOBAL source address, LDS dest linear (rule #21).
#define BM 128
#define BN 128

__global__ __launch_bounds__(256, 2) void vq_argmin(
    const float* __restrict__ z, const float* __restrict__ cb,
    const unsigned short* __restrict__ cbh, const unsigned short* __restrict__ cbl,
    const float* __restrict__ z2, const float* __restrict__ e2,
    unsigned int* __restrict__ hist, float* __restrict__ loss_sum,
    unsigned int* __restrict__ flag_cnt, unsigned int* __restrict__ flag_list,
    float* __restrict__ out)
{
    // LDS: 4 bf16 tiles [128 rows][128B] (Ah,Al,Bh,Bl) = 64KB, reused as red.
    __shared__ __align__(16) char sm[65536];
    __shared__ int kwin[BM];
    __shared__ unsigned char flgs[BM];
    __shared__ float wred[4];

    const int tid = threadIdx.x;
    const int lane = tid & 63;
    const int wid = tid >> 6;
    const int wm = wid >> 1, wn = wid & 1;
    const int col = lane & 15;      // frag column
    const int lg  = lane >> 4;      // k-group
    const int swz = lane & 7;
    const int row0 = blockIdx.x * BM;

    const char* zsB  = (const char*)out;       // zh/zl packed rows (1KB/row)
    const char* cbhB = (const char*)cbh;       // 512B/row
    const char* cblB = (const char*)cbl;

    // persistent per-thread state: 16 pixels x (best, 2nd-best, idx)
    float b1[16], b2[16]; int i1[16];
    float z2r[16];
    #pragma unroll
    for (int q = 0; q < 16; ++q) {
        b1[q] = FLT_MAX; b2[q] = FLT_MAX; i1[q] = 0;
        z2r[q] = z2[row0 + wm * 64 + (q >> 2) * 16 + lg * 4 + (q & 3)];
    }

    int aRow[4], bRow[4];
    #pragma unroll
    for (int f = 0; f < 4; ++f) {
        aRow[f] = (wm * 64 + f * 16 + col) * 128;   // byte base of LDS row
        bRow[f] = (wn * 64 + f * 16 + col) * 128;
    }
    const int bc0 = ((0 + lg) ^ swz) << 4;          // swizzled 16B col, ks=0
    const int bc1 = ((4 + lg) ^ swz) << 4;          // ks=1

    const int sr  = lane >> 3;                      // staging sub-row 0..7
    const int scb = lane & 7;                       // staging phys 16B block

    #pragma unroll 1
    for (int nc = 0; nc < KTOT / BN; ++nc) {
        const int n0 = nc * BN;
        f32x4 acc[4][4];
        #pragma unroll
        for (int fm = 0; fm < 4; ++fm)
            #pragma unroll
            for (int fn = 0; fn < 4; ++fn)
                acc[fm][fn] = (f32x4){0.0f, 0.0f, 0.0f, 0.0f};

        #pragma unroll 1
        for (int kc = 0; kc < 4; ++kc) {            // BK=64
            __syncthreads();
            // --- stage: 16 x global_load_lds (4 tiles x 4 row-slabs) -------
            #pragma unroll
            for (int i = 0; i < 4; ++i) {
                const int rloc = wid * 32 + i * 8 + sr;           // 0..127
                const int cb16 = ((scb ^ (rloc & 7)) << 4);       // src block
                const size_t aoff = ((size_t)(row0 + rloc) << 10) + (kc << 7);
                const size_t boff = ((size_t)(n0 + rloc) << 9) + (kc << 7);
                char* lb = sm + (wid * 32 + i * 8) * 128;         // uniform
                gl16(zsB + aoff + cb16,        lb);               // Ah @ 0
                gl16(zsB + aoff + 512 + cb16,  lb + 16384);       // Al @ 16K
                gl16(cbhB + boff + cb16,       lb + 32768);       // Bh @ 32K
                gl16(cblB + boff + cb16,       lb + 49152);       // Bl @ 48K
            }
            __syncthreads();   // drains vmcnt -> tiles visible
            // --- MFMA: 3-term bf16x2 split into shared f32 accumulator ----
            #pragma unroll
            for (int ks = 0; ks < 2; ++ks) {
                const int bc = ks ? bc1 : bc0;
                s16x8 ah[4], al[4], bh[4], bl[4];
                #pragma unroll
                for (int f = 0; f < 4; ++f) {
                    ah[f] = *(const s16x8*)(sm + aRow[f] + bc);
                    al[f] = *(const s16x8*)(sm + 16384 + aRow[f] + bc);
                    bh[f] = *(const s16x8*)(sm + 32768 + bRow[f] + bc);
                    bl[f] = *(const s16x8*)(sm + 49152 + bRow[f] + bc);
                }
                #pragma unroll
                for (int fm = 0; fm < 4; ++fm)
                    #pragma unroll
                    for (int fn = 0; fn < 4; ++fn) {
                        acc[fm][fn] = __builtin_amdgcn_mfma_f32_16x16x32_bf16(
                            ah[fm], bh[fn], acc[fm][fn], 0, 0, 0);
                        acc[fm][fn] = __builtin_amdgcn_mfma_f32_16x16x32_bf16(
                            ah[fm], bl[fn], acc[fm][fn], 0, 0, 0);
                        acc[fm][fn] = __builtin_amdgcn_mfma_f32_16x16x32_bf16(
                            al[fm], bh[fn], acc[fm][fn], 0, 0, 0);
                    }
            }
        }
        // --- fold chunk into running (best, 2nd); ref dist rounding --------
        float e2v[4];
        #pragma unroll
        for (int fn = 0; fn < 4; ++fn) e2v[fn] = e2[n0 + wn * 64 + fn * 16 + col];
        #pragma unroll
        for (int fm = 0; fm < 4; ++fm)
            #pragma unroll
            for (int fn = 0; fn < 4; ++fn)
                #pragma unroll
                for (int r4 = 0; r4 < 4; ++r4) {
                    const int q = fm * 4 + r4;
                    const float dist = (z2r[q] + e2v[fn]) - 2.0f * acc[fm][fn][r4];
                    const int idx = n0 + wn * 64 + fn * 16 + col;
                    if (dist < b1[q]) { b2[q] = b1[q]; b1[q] = dist; i1[q] = idx; }
                    else if (dist < b2[q]) { b2[q] = dist; }
                }
    }

    // --- cross-thread reduction of (b1,i1,b2); slots padded to 33 ----------
    __syncthreads();
    float* Rb1 = (float*)sm;                 // [128][33]
    float* Rb2 = (float*)(sm + 16896);
    int*   Ri1 = (int*)(sm + 33792);
    const int slot = col + 16 * wn;          // 0..31
    #pragma unroll
    for (int q = 0; q < 16; ++q) {
        const int px = wm * 64 + (q >> 2) * 16 + lg * 4 + (q & 3);
        Rb1[px * 33 + slot] = b1[q];
        Rb2[px * 33 + slot] = b2[q];
        Ri1[px * 33 + slot] = i1[q];
    }
    __syncthreads();
    if (tid < BM) {
        float x1 = Rb1[tid * 33], x2 = Rb2[tid * 33]; int xi = Ri1[tid * 33];
        for (int s = 1; s < 32; ++s) {
            const float c1 = Rb1[tid * 33 + s], c2 = Rb2[tid * 33 + s];
            const int ci = Ri1[tid * 33 + s];
            const float nb2 = fminf(fmaxf(x1, c1), fminf(x2, c2));
            if (c1 < x1 || (c1 == x1 && ci < xi)) { x1 = c1; xi = ci; }
            x2 = nb2;
        }
        kwin[tid] = xi;
        const bool fl = (x2 - x1) <= MARGIN_;
        flgs[tid] = fl ? 1 : 0;
        if (fl) {
            const unsigned pos = atomicAdd(flag_cnt, 1u);
            flag_list[pos] = (unsigned)(row0 + tid);
        } else {
            out[OUT_IDX_OFF + row0 + tid] = (float)xi;
            atomicAdd(&hist[xi], 1u);
        }
    }
    __syncthreads();

    // --- epilogue for UNFLAGGED rows (exact fp32, ref rounding) ------------
    // overwrites this block's zh/zl scratch with the real z_q_st.
    float lacc = 0.0f;
    #pragma unroll 4
    for (int i = 0; i < 32; ++i) {
        const int flat4 = tid + i * 256;
        const int row = flat4 >> 6;            // wave-uniform
        if (!flgs[row]) {
            const int dj = (flat4 & 63) * 4;
            const size_t zoff = (size_t)(row0 + row) * DIM + dj;
            float4 zv = *(const float4*)(z + zoff);
            float4 ev = *(const float4*)(cb + (size_t)kwin[row] * DIM + dj);
            float dx = ev.x - zv.x, dy = ev.y - zv.y, dz = ev.z - zv.z, dw = ev.w - zv.w;
            float4 o;
            o.x = zv.x + dx; o.y = zv.y + dy; o.z = zv.z + dz; o.w = zv.w + dw;
            *(float4*)(out + zoff) = o;
            lacc += dx * dx + dy * dy + dz * dz + dw * dw;
        }
    }
    #pragma unroll
    for (int off = 32; off > 0; off >>= 1) lacc += __shfl_down(lacc, off, 64);
    if (lane == 0) wred[wid] = lacc;
    __syncthreads();
    if (tid == 0) atomicAdd(loss_sum, wred[0] + wred[1] + wred[2] + wred[3]);
}

// ---------------- repair: exact fp32 re-argmin + epilogue for flagged ------
// Bit-identical to the verified baseline's fp32 path: d-ascending fma chain,
// dist = (z2+e2[k]) - 2*dot, tie -> smaller index.
__global__ __launch_bounds__(256) void vq_fix(
    const float* __restrict__ z, const float* __restrict__ cb,
    const float* __restrict__ z2, const float* __restrict__ e2,
    const unsigned int* __restrict__ flag_cnt, const unsigned int* __restrict__ flag_list,
    unsigned int* __restrict__ hist, float* __restrict__ loss_sum,
    float* __restrict__ out)
{
    __shared__ float zrow[4][DIM];
    __shared__ float zz2[4];
    __shared__ int pxid[4];
    __shared__ float rb[4][256];
    __shared__ int   ri[4][256];
    __shared__ int   kw4[4];

    const int tid = threadIdx.x;
    const int total = (int)*flag_cnt;

    for (int base = blockIdx.x * 4; base < total; base += gridDim.x * 4) {
        const int npx = min(4, total - base);
        __syncthreads();                       // protect prev iter's shared
        if (tid < 4) {
            const int p = (int)flag_list[base + (tid < npx ? tid : 0)];
            pxid[tid] = p; zz2[tid] = z2[p];
        }
        __syncthreads();
        {
            const int q = tid >> 6, d = (tid & 63) * 4;
            float4 v = *(const float4*)(z + (size_t)pxid[q] * DIM + d);
            *(float4*)&zrow[q][d] = v;
        }
        __syncthreads();

        const int k0 = tid * 4;
        float acc[4][4];
        #pragma unroll
        for (int q = 0; q < 4; ++q)
            #pragma unroll
            for (int j = 0; j < 4; ++j) acc[q][j] = 0.0f;

        for (int d4 = 0; d4 < 64; ++d4) {
            float4 cv[4];
            #pragma unroll
            for (int j = 0; j < 4; ++j)
                cv[j] = *(const float4*)(cb + (size_t)(k0 + j) * DIM + d4 * 4);
            #pragma unroll
            for (int q = 0; q < 4; ++q) {
                float4 zv = *(const float4*)&zrow[q][d4 * 4];
                #pragma unroll
                for (int j = 0; j < 4; ++j) {
                    acc[q][j] = fmaf(zv.x, cv[j].x, acc[q][j]);
                    acc[q][j] = fmaf(zv.y, cv[j].y, acc[q][j]);
                    acc[q][j] = fmaf(zv.z, cv[j].z, acc[q][j]);
                    acc[q][j] = fmaf(zv.w, cv[j].w, acc[q][j]);
                }
            }
        }
        #pragma unroll
        for (int q = 0; q < 4; ++q) {
            float bd = FLT_MAX; int bi = 0;
            #pragma unroll
            for (int j = 0; j < 4; ++j) {       // k ascending -> strict <
                const int k = k0 + j;
                const float dist = (zz2[q] + e2[k]) - 2.0f * acc[q][j];
                if (dist < bd) { bd = dist; bi = k; }
            }
            rb[q][tid] = bd; ri[q][tid] = bi;
        }
        __syncthreads();
        {
            const int q = tid >> 6, lane = tid & 63;
            float bd = rb[q][lane]; int bi = ri[q][lane];
            #pragma unroll
            for (int s = 1; s < 4; ++s) {
                const float d2 = rb[q][lane + s * 64]; const int i2 = ri[q][lane + s * 64];
                if (d2 < bd || (d2 == bd && i2 < bi)) { bd = d2; bi = i2; }
            }
            #pragma unroll
            for (int off = 32; off > 0; off >>= 1) {
                const float d2 = __shfl_down(bd, off, 64);
                const int i2 = __shfl_down(bi, off, 64);
                if (d2 < bd || (d2 == bd && i2 < bi)) { bd = d2; bi = i2; }
            }
            if (lane == 0) kw4[q] = bi;
        }
        __syncthreads();
        {
            const int q = tid >> 6, lane = tid & 63;
            if (q < npx) {
                const int p = pxid[q];
                const int kw = kw4[q];
                const int d = lane * 4;
                float4 zv = *(const float4*)&zrow[q][d];
                float4 ev = *(const float4*)(cb + (size_t)kw * DIM + d);
                float dx = ev.x - zv.x, dy = ev.y - zv.y, dz = ev.z - zv.z, dw = ev.w - zv.w;
                float4 o;
                o.x = zv.x + dx; o.y = zv.y + dy; o.z = zv.z + dz; o.w = zv.w + dw;
                *(float4*)(out + (size_t)p * DIM + d) = o;
                float lacc = dx * dx + dy * dy + dz * dz + dw * dw;
                #pragma unroll
                for (int off = 32; off > 0; off >>= 1) lacc += __shfl_down(lacc, off, 64);
                if (lane == 0) {
                    atomicAdd(loss_sum, lacc);
                    out[OUT_IDX_OFF + p] = (float)kw;
                    atomicAdd(&hist[kw], 1u);
                }
            }
        }
    }
}

// ---------------- finalize: losses + perplexity -----------------------------
__global__ __launch_bounds__(1024) void vq_finalize(
    const unsigned int* __restrict__ hist, const float* __restrict__ loss_sum,
    float* __restrict__ out)
{
    __shared__ float sred[16];
    __shared__ float totalsh;
    const int tid = threadIdx.x;
    const float c = (float)hist[tid];

    float t = c;
    #pragma unroll
    for (int off = 32; off > 0; off >>= 1) t += __shfl_down(t, off, 64);
    if ((tid & 63) == 0) sred[tid >> 6] = t;
    __syncthreads();
    if (tid == 0) {
        float s = 0.0f;
        for (int i = 0; i < 16; ++i) s += sred[i];
        totalsh = s;
    }
    __syncthreads();
    const float total = totalsh;
    const float prob = c / (total + EPS_);
    float term = prob * logf(prob + EPS_);
    __syncthreads();
    #pragma unroll
    for (int off = 32; off > 0; off >>= 1) term += __shfl_down(term, off, 64);
    if ((tid & 63) == 0) sred[tid >> 6] = term;
    __syncthreads();
    if (tid == 0) {
        float s = 0.0f;
        for (int i = 0; i < 16; ++i) s += sred[i];
        const float perp = expf(-s);
        const float S = *loss_sum;
        const float mean = S / (float)(P_TOT * DIM);
        out[OUT_LOSS_OFF + 0] = mean;                  // commitment_loss
        out[OUT_LOSS_OFF + 1] = mean;                  // codebook_loss
        out[OUT_LOSS_OFF + 2] = mean + BETA_ * mean;   // cluster_loss
        out[OUT_LOSS_OFF + 3] = perp;                  // perplexity
    }
}

extern "C" void kernel_launch(void* const* d_in, const int* in_sizes, int n_in,
                              void* d_out, int out_size, void* d_ws, size_t ws_size,
                              hipStream_t stream) {
    const float* z  = (const float*)d_in[0];
    const float* cb = (const float*)d_in[1];
    float* out = (float*)d_out;

    // ws: z2[P] | e2[K] | hist[K] | loss_sum | flag_cnt | flag_list[P] |
    //     cbh[K*D] bf16 | cbl[K*D] bf16   (~1.9 MiB)
    float* z2 = (float*)d_ws;
    float* e2 = z2 + P_TOT;
    unsigned int* hist = (unsigned int*)(e2 + KTOT);
    float* loss_sum = (float*)(hist + KTOT);
    unsigned int* flag_cnt = (unsigned int*)(loss_sum + 1);
    unsigned int* flag_list = flag_cnt + 1;
    unsigned short* cbh = (unsigned short*)(((uintptr_t)(flag_list + P_TOT) + 15) & ~(uintptr_t)15);
    unsigned short* cbl = cbh + (size_t)KTOT * DIM;

    vq_prep<<<KTOT, 64, 0, stream>>>(cb, e2, cbh, cbl, hist, loss_sum, flag_cnt);
    vq_zsplit<<<P_TOT / 4, 256, 0, stream>>>(z, z2, out);
    vq_argmin<<<P_TOT / BM, 256, 0, stream>>>(z, cb, cbh, cbl, z2, e2,
                                              hist, loss_sum, flag_cnt, flag_list, out);
    vq_fix<<<1024, 256, 0, stream>>>(z, cb, z2, e2, flag_cnt, flag_list,
                                     hist, loss_sum, out);
    vq_finalize<<<1, 1024, 0, stream>>>(hist, loss_sum, out);
}